// Round 13
// baseline (112.736 us; speedup 1.0000x reference)
//
#include <hip/hip_runtime.h>

typedef __attribute__((ext_vector_type(8))) short bf16x8;
typedef __attribute__((ext_vector_type(4))) float f32x4;
typedef __attribute__((ext_vector_type(16))) float f32x16;

#define BATCH 2
#define SEQ 2048
#define DMODEL 768
#define NH 12
#define HD 64
#define M_TOK (BATCH * SEQ)   /* 4096 */
#define N_KQV (3 * DMODEL)    /* 2304 */

#define GLOAD16(gsrc, ldst) __builtin_amdgcn_global_load_lds( \
    (const __attribute__((address_space(1))) unsigned int*)(const void*)(gsrc), \
    (__attribute__((address_space(3))) unsigned int*)(void*)(ldst), 16, 0, 0)

__device__ __forceinline__ unsigned short f2bf(float f) {
  unsigned int u = __float_as_uint(f);
  u += 0x7FFFu + ((u >> 16) & 1u);
  return (unsigned short)(u >> 16);
}

__device__ __forceinline__ unsigned int cvtpk(float lo, float hi) {
  unsigned int r;
  asm("v_cvt_pk_bf16_f32 %0, %1, %2" : "=v"(r) : "v"(lo), "v"(hi));
  return r;
}

// ---------------- conversion kernels ----------------

__global__ void cvt_f32_bf16(const float* __restrict__ in,
                             unsigned short* __restrict__ out, int n4) {
  int i = blockIdx.x * blockDim.x + threadIdx.x;
  if (i >= n4) return;
  float4 v = reinterpret_cast<const float4*>(in)[i];
  unsigned long long p = (unsigned long long)f2bf(v.x)
                       | ((unsigned long long)f2bf(v.y) << 16)
                       | ((unsigned long long)f2bf(v.z) << 32)
                       | ((unsigned long long)f2bf(v.w) << 48);
  reinterpret_cast<unsigned long long*>(out)[i] = p;
}

// out[c][r] = bf16(in[r][c]); rows, cols divisible by 32
__global__ void transpose_cvt(const float* __restrict__ in,
                              unsigned short* __restrict__ out,
                              int rows, int cols) {
  __shared__ float tile[32][33];
  int c0 = blockIdx.x * 32, r0 = blockIdx.y * 32;
  for (int i = threadIdx.y; i < 32; i += 8)
    tile[i][threadIdx.x] = in[(size_t)(r0 + i) * cols + c0 + threadIdx.x];
  __syncthreads();
  for (int i = threadIdx.y; i < 32; i += 8)
    out[(size_t)(c0 + i) * rows + r0 + threadIdx.x] = f2bf(tile[threadIdx.x][i]);
}

// ---------------- GEMM: C[M,N] = A[M,K] @ BT[N,K]^T + bias ----------------
// 4 waves (2m x 2n); wave computes 32 x (BN/2) via 32x32x16 MFMA.
// DEPTH-3 pipeline: 3 LDS stage buffers, counted vmcnt. Issue->wait gap
// = ~2 iters (~2000 cyc) > HBM latency (~900 cyc), so the wait is free.
// Per iter: vmcnt(2L) -> barrier -> ds_read+MFMA -> barrier -> STAGE(kt+3).
template <int BM, int BN, int MODE>
__global__ __launch_bounds__(256) void gemm_bt(
    const unsigned short* __restrict__ A,   // [M][K] bf16
    const unsigned short* __restrict__ BT,  // [N][K] bf16
    const float* __restrict__ bias,         // [N]
    int M, int N, int K,
    unsigned short* __restrict__ outK, unsigned short* __restrict__ outQ,
    unsigned short* __restrict__ outVT, float* __restrict__ outF) {
  constexpr int WTN = BN / 2;
  constexpr int NACC = WTN / 32;
  constexpr int L = BM / 64 + BN / 64;   // own-wave gload_lds per stage
  __shared__ __align__(16) unsigned short lds_a[3][BM][32];
  __shared__ __align__(16) unsigned short lds_b[3][BN][32];
  const int tid = threadIdx.x;
  const int lane = tid & 63;
  const int w = tid >> 6;
  const int wm = w >> 1, wn = w & 1;
  const int l31 = lane & 31, hi = lane >> 5;
  const int m0 = blockIdx.y * BM, n0 = blockIdx.x * BN;

  f32x16 acc[NACC];
#pragma unroll
  for (int j = 0; j < NACC; j++)
#pragma unroll
    for (int i = 0; i < 16; i++) acc[j][i] = 0.f;

  const int srow = lane >> 2;                               // 0..15 in wave band
  const int sg = ((lane & 3) ^ ((lane >> 3) & 3)) * 8;      // swizzled global k-chunk
  const int xq = (l31 >> 1) & 3;                            // read-side XOR

#define STAGE(buf, k0)                                                        \
  {                                                                           \
    _Pragma("unroll")                                                         \
    for (int rr = 0; rr < BM / 64; ++rr)                                      \
      GLOAD16(&A[(size_t)(m0 + rr * 64 + w * 16 + srow) * K + (k0) + sg],     \
              &lds_a[buf][rr * 64 + w * 16][0]);                              \
    _Pragma("unroll")                                                         \
    for (int rr = 0; rr < BN / 64; ++rr)                                      \
      GLOAD16(&BT[(size_t)(n0 + rr * 64 + w * 16 + srow) * K + (k0) + sg],    \
              &lds_b[buf][rr * 64 + w * 16][0]);                              \
  }

  const int KT = K >> 5;   // 24 for K=768, always >= 3
  STAGE(0, 0);
  STAGE(1, 32);
  STAGE(2, 64);

  int cur = 0;
  for (int kt = 0; kt < KT; ++kt) {
    // wait for stage kt only; up to 2 newer stages stay in flight
    if (kt + 2 < KT) {
      if constexpr (L == 3) asm volatile("s_waitcnt vmcnt(6)" ::: "memory");
      else                  asm volatile("s_waitcnt vmcnt(4)" ::: "memory");
    } else if (kt + 1 < KT) {
      if constexpr (L == 3) asm volatile("s_waitcnt vmcnt(3)" ::: "memory");
      else                  asm volatile("s_waitcnt vmcnt(2)" ::: "memory");
    } else {
      asm volatile("s_waitcnt vmcnt(0)" ::: "memory");
    }
    __builtin_amdgcn_s_barrier();          // all waves' stage-kt loads landed
    __builtin_amdgcn_sched_barrier(0);     // pin ds_reads below the barrier

    bf16x8 aA[2], aB[2][NACC];
#pragma unroll
    for (int ds = 0; ds < 2; ds++) {
      const int rc = ((ds * 2 + hi) ^ xq) * 8;   // swizzled read chunk (shorts)
      aA[ds] = *(const bf16x8*)&lds_a[cur][wm * 32 + l31][rc];
#pragma unroll
      for (int j = 0; j < NACC; j++)
        aB[ds][j] = *(const bf16x8*)&lds_b[cur][wn * WTN + j * 32 + l31][rc];
    }
#pragma unroll
    for (int ds = 0; ds < 2; ds++)
#pragma unroll
      for (int j = 0; j < NACC; j++)
        acc[j] = __builtin_amdgcn_mfma_f32_32x32x16_bf16(aA[ds], aB[ds][j], acc[j], 0, 0, 0);

    __builtin_amdgcn_s_barrier();          // all waves done reading buf[cur]
    __builtin_amdgcn_sched_barrier(0);     // keep the overwrite below the barrier
    if (kt + 3 < KT) STAGE(cur, (kt + 3) << 5);
    cur = (cur == 2) ? 0 : cur + 1;
  }
#undef STAGE

#pragma unroll
  for (int j = 0; j < NACC; j++) {
#pragma unroll
    for (int r = 0; r < 16; r++) {
      int row = m0 + wm * 32 + (r & 3) + 8 * (r >> 2) + 4 * hi;
      int col = n0 + wn * WTN + j * 32 + l31;
      float v = acc[j][r] + bias[col];
      if (MODE == 0) {
        int chunk = col / DMODEL;          // 0=k, 1=q, 2=v
        int d = col - chunk * DMODEL;
        int hh = d >> 6, di = d & 63;
        int bb = row >> 11, tok = row & 2047;
        int bh = bb * NH + hh;
        if (chunk == 0)
          outK[((size_t)bh * SEQ + tok) * HD + di] = f2bf(v);
        else if (chunk == 1)
          outQ[((size_t)bh * SEQ + tok) * HD + di] = f2bf(v * 0.125f);
        else
          outVT[((size_t)bh * HD + di) * SEQ + tok] = f2bf(v);
      } else {
        outF[(size_t)row * N + col] = v;
      }
    }
  }
}

// ---------------- flash attention (round-8 verified: 43.5 us) ----------------
// grid 1536 (64 q-tiles x 24 heads), XCD-affine; dispatch order t-MAJOR
// interleaved across heads (3 longest blocks per XCD launch first).
// Swapped QK^T (S^T = mfma(K,Q)): P lane-local -> in-register softmax,
// pack via cvt_pk + permlane32_swap (swap(X,Y) -> ret0={Xlo,Ylo}, ret1={Xhi,Yhi}).
__global__ __launch_bounds__(128) void attn_kernel(
    const unsigned short* __restrict__ qbuf,  // [BH][SEQ][HD], pre-scaled by 1/8
    const unsigned short* __restrict__ kbuf,  // [BH][SEQ][HD]
    const unsigned short* __restrict__ vT,    // [BH][HD][SEQ]
    unsigned short* __restrict__ sa) {        // [B][SEQ][DMODEL]
  __shared__ __align__(16) char smem_raw[18432];
  auto k_lds = reinterpret_cast<unsigned short (*)[72]>(smem_raw);            // [64][72]
  auto v_lds = reinterpret_cast<unsigned short (*)[72]>(smem_raw + 9216);     // [64][72]
  auto o_merge = reinterpret_cast<float (*)[32][33]>(smem_raw);               // [2][32][33] (aliases k_lds)
  auto l_merge = reinterpret_cast<float (*)[32]>(smem_raw + 9216);            // [2][32]     (aliases v_lds)

  const int tid = threadIdx.x, lane = tid & 63, w = tid >> 6;
  const int l31 = lane & 31, hi = lane >> 5;

  // XCD-affine remap: fid%8 == XCD; 3 heads/XCD; t-major longest-first
  const int fid = (int)blockIdx.y * (int)gridDim.x + (int)blockIdx.x;  // 0..1535
  const int xcd = fid & 7, slot = fid >> 3;       // slot 0..191
  const int head3 = slot % 3;
  const int t = 63 - slot / 3;                    // 32-row q-tile, longest first
  const int bh = head3 * 8 + xcd;                 // 0..23
  const int ktmax = t >> 1;                       // inclusive last 64-key tile

  const size_t qk_base = (size_t)bh * SEQ * HD;
  const size_t v_base = (size_t)bh * HD * SEQ;
  const int bb = bh / NH, h = bh - bb * NH;

  const int sr = w * 32 + (lane >> 3);
  const int sc = (lane & 7) * 8;

  {  // prologue: stage k-tile 0
    bf16x8 rk[4], rv[4];
#pragma unroll
    for (int p = 0; p < 4; p++) {
      rk[p] = *(const bf16x8*)&kbuf[qk_base + (size_t)(sr + 8 * p) * HD + sc];
      rv[p] = *(const bf16x8*)&vT[v_base + (size_t)(sr + 8 * p) * SEQ + sc];
    }
#pragma unroll
    for (int p = 0; p < 4; p++) {
      *(bf16x8*)&k_lds[sr + 8 * p][sc] = rk[p];
      *(bf16x8*)&v_lds[sr + 8 * p][sc] = rv[p];
    }
  }

  bf16x8 aq[4];
#pragma unroll
  for (int ds = 0; ds < 4; ds++)
    aq[ds] = *(const bf16x8*)&qbuf[qk_base + (size_t)(t * 32 + l31) * HD + ds * 16 + hi * 8];

  f32x16 o0, o1;
#pragma unroll
  for (int i = 0; i < 16; i++) { o0[i] = 0.f; o1[i] = 0.f; }
  float lsum = 0.f;

  __syncthreads();

  for (int kt = 0; kt <= ktmax; ++kt) {
    const bool more = (kt < ktmax);
    // ---- prefetch next tile's K/V into registers (coalesced) ----
    bf16x8 rk[4], rv[4];
    if (more) {
      const int nrow = (kt + 1) * 64;
#pragma unroll
      for (int p = 0; p < 4; p++) {
        rk[p] = *(const bf16x8*)&kbuf[qk_base + (size_t)(nrow + sr + 8 * p) * HD + sc];
        rv[p] = *(const bf16x8*)&vT[v_base + (size_t)(sr + 8 * p) * SEQ + nrow + sc];
      }
    }

    // ---- S^T[32k x 32q] = K @ Q^T (wave's 32-key window) ----
    f32x16 s;
#pragma unroll
    for (int i = 0; i < 16; i++) s[i] = 0.f;
    __builtin_amdgcn_s_setprio(1);
#pragma unroll
    for (int ds = 0; ds < 4; ds++) {
      bf16x8 bk = *(const bf16x8*)&k_lds[w * 32 + l31][ds * 16 + hi * 8];
      s = __builtin_amdgcn_mfma_f32_32x32x16_bf16(bk, aq[ds], s, 0, 0, 0);
    }
    __builtin_amdgcn_s_setprio(0);

    // ---- mask + fixed-shift exp (in registers); accumulate denominator ----
    const bool diag = (kt == ktmax);
    const int qb2 = (t & 1) * 32;
#pragma unroll
    for (int r = 0; r < 16; r++) {
      int kr = (r & 3) + 8 * (r >> 2) + 4 * hi;   // key row within wave window
      float val = s[r];
      if (diag && (w * 32 + kr > qb2 + l31)) val = -1e30f;
      float p = __expf(val);
      s[r] = p;
      lsum += p;
    }

    // ---- pack P -> PV A-fragments ----
    union { unsigned int u[4]; bf16x8 v; } f1, f2;
    {
      unsigned int A = cvtpk(s[0], s[1]), B = cvtpk(s[2], s[3]);
      unsigned int C = cvtpk(s[4], s[5]), D = cvtpk(s[6], s[7]);
      auto rAC = __builtin_amdgcn_permlane32_swap(A, C, false, false);
      auto rBD = __builtin_amdgcn_permlane32_swap(B, D, false, false);
      f1.u[0] = rAC[0]; f1.u[1] = rBD[0]; f1.u[2] = rAC[1]; f1.u[3] = rBD[1];
      unsigned int A2 = cvtpk(s[8], s[9]),   B2 = cvtpk(s[10], s[11]);
      unsigned int C2 = cvtpk(s[12], s[13]), D2 = cvtpk(s[14], s[15]);
      auto rAC2 = __builtin_amdgcn_permlane32_swap(A2, C2, false, false);
      auto rBD2 = __builtin_amdgcn_permlane32_swap(B2, D2, false, false);
      f2.u[0] = rAC2[0]; f2.u[1] = rBD2[0]; f2.u[2] = rAC2[1]; f2.u[3] = rBD2[1];
    }

    // ---- O += P @ V (two 16-k windows x two 32-d blocks) ----
    __builtin_amdgcn_s_setprio(1);
    {
      bf16x8 bv00 = *(const bf16x8*)&v_lds[l31][w * 32 + hi * 8];
      bf16x8 bv01 = *(const bf16x8*)&v_lds[32 + l31][w * 32 + hi * 8];
      o0 = __builtin_amdgcn_mfma_f32_32x32x16_bf16(f1.v, bv00, o0, 0, 0, 0);
      o1 = __builtin_amdgcn_mfma_f32_32x32x16_bf16(f1.v, bv01, o1, 0, 0, 0);
      bf16x8 bv10 = *(const bf16x8*)&v_lds[l31][w * 32 + 16 + hi * 8];
      bf16x8 bv11 = *(const bf16x8*)&v_lds[32 + l31][w * 32 + 16 + hi * 8];
      o0 = __builtin_amdgcn_mfma_f32_32x32x16_bf16(f2.v, bv10, o0, 0, 0, 0);
      o1 = __builtin_amdgcn_mfma_f32_32x32x16_bf16(f2.v, bv11, o1, 0, 0, 0);
    }
    __builtin_amdgcn_s_setprio(0);

    // ---- stage prefetched tile ----
    if (more) {
      __syncthreads();
#pragma unroll
      for (int p = 0; p < 4; p++) {
        *(bf16x8*)&k_lds[sr + 8 * p][sc] = rk[p];
        *(bf16x8*)&v_lds[sr + 8 * p][sc] = rv[p];
      }
      __syncthreads();
    }
  }

  // ---- merge wave partials (LDS aliased over dead k/v tiles) ----
  __syncthreads();
  {
    float ltot = lsum + __shfl_xor(lsum, 32);
    if (hi == 0) l_merge[w][l31] = ltot;
    f32x16 osend = w ? o0 : o1;
#pragma unroll
    for (int r = 0; r < 16; r++) {
      int ql = (r & 3) + 8 * (r >> 2) + 4 * hi;
      o_merge[w][ql][l31] = osend[r];
    }
    __syncthreads();
    f32x16 okeep = w ? o1 : o0;
#pragma unroll
    for (int r = 0; r < 16; r++) {
      int ql = (r & 3) + 8 * (r >> 2) + 4 * hi;
      float ot = okeep[r] + o_merge[1 - w][ql][l31];
      float lt = l_merge[0][ql] + l_merge[1][ql];
      sa[((size_t)bb * SEQ + t * 32 + ql) * DMODEL + h * HD + w * 32 + l31] = f2bf(ot / lt);
    }
  }
}

// ---------------- launch ----------------

extern "C" void kernel_launch(void* const* d_in, const int* in_sizes, int n_in,
                              void* d_out, int out_size, void* d_ws, size_t ws_size,
                              hipStream_t stream) {
  const float* x     = (const float*)d_in[0];
  const float* Wkqv  = (const float*)d_in[1];
  const float* bkqv  = (const float*)d_in[2];
  const float* Wproj = (const float*)d_in[3];
  const float* bproj = (const float*)d_in[4];
  float* out = (float*)d_out;

  char* ws = (char*)d_ws;
  unsigned short* x_bf   = (unsigned short*)(ws + 0);
  unsigned short* wkqvT  = (unsigned short*)(ws + 6291456);
  unsigned short* wprojT = (unsigned short*)(ws + 9830400);
  unsigned short* qb     = (unsigned short*)(ws + 11010048);
  unsigned short* kb     = (unsigned short*)(ws + 17301504);
  unsigned short* vT     = (unsigned short*)(ws + 23592960);
  unsigned short* sa     = (unsigned short*)(ws + 29884416);

  cvt_f32_bf16<<<(M_TOK * DMODEL / 4 + 255) / 256, 256, 0, stream>>>(x, x_bf, M_TOK * DMODEL / 4);
  transpose_cvt<<<dim3(N_KQV / 32, DMODEL / 32), dim3(32, 8), 0, stream>>>(Wkqv, wkqvT, DMODEL, N_KQV);
  transpose_cvt<<<dim3(DMODEL / 32, DMODEL / 32), dim3(32, 8), 0, stream>>>(Wproj, wprojT, DMODEL, DMODEL);

  // GEMM1: 64x128 tiles -> 1152 blocks (4.5/CU)
  gemm_bt<64, 128, 0><<<dim3(N_KQV / 128, M_TOK / 64), 256, 0, stream>>>(
      x_bf, wkqvT, bkqv, M_TOK, N_KQV, DMODEL, kb, qb, vT, nullptr);

  attn_kernel<<<dim3(64, BATCH * NH), 128, 0, stream>>>(qb, kb, vT, sa);

  // GEMM2: 64x64 tiles -> 768 blocks (3/CU)
  gemm_bt<64, 64, 1><<<dim3(DMODEL / 64, M_TOK / 64), 256, 0, stream>>>(
      sa, wprojT, bproj, M_TOK, DMODEL, DMODEL, nullptr, nullptr, nullptr, out);
}

// Round 14
// 107.858 us; speedup vs baseline: 1.0452x; 1.0452x over previous
//
#include <hip/hip_runtime.h>

typedef __attribute__((ext_vector_type(8))) short bf16x8;
typedef __attribute__((ext_vector_type(4))) float f32x4;
typedef __attribute__((ext_vector_type(16))) float f32x16;

#define BATCH 2
#define SEQ 2048
#define DMODEL 768
#define NH 12
#define HD 64
#define M_TOK (BATCH * SEQ)   /* 4096 */
#define N_KQV (3 * DMODEL)    /* 2304 */

#define GLOAD16(gsrc, ldst) __builtin_amdgcn_global_load_lds( \
    (const __attribute__((address_space(1))) unsigned int*)(const void*)(gsrc), \
    (__attribute__((address_space(3))) unsigned int*)(void*)(ldst), 16, 0, 0)

__device__ __forceinline__ unsigned short f2bf(float f) {
  unsigned int u = __float_as_uint(f);
  u += 0x7FFFu + ((u >> 16) & 1u);
  return (unsigned short)(u >> 16);
}

__device__ __forceinline__ unsigned int cvtpk(float lo, float hi) {
  unsigned int r;
  asm("v_cvt_pk_bf16_f32 %0, %1, %2" : "=v"(r) : "v"(lo), "v"(hi));
  return r;
}

// ---------------- conversion kernels ----------------

__global__ void cvt_f32_bf16(const float* __restrict__ in,
                             unsigned short* __restrict__ out, int n4) {
  int i = blockIdx.x * blockDim.x + threadIdx.x;
  if (i >= n4) return;
  float4 v = reinterpret_cast<const float4*>(in)[i];
  unsigned long long p = (unsigned long long)f2bf(v.x)
                       | ((unsigned long long)f2bf(v.y) << 16)
                       | ((unsigned long long)f2bf(v.z) << 32)
                       | ((unsigned long long)f2bf(v.w) << 48);
  reinterpret_cast<unsigned long long*>(out)[i] = p;
}

// out[c][r] = bf16(in[r][c]); rows, cols divisible by 32
__global__ void transpose_cvt(const float* __restrict__ in,
                              unsigned short* __restrict__ out,
                              int rows, int cols) {
  __shared__ float tile[32][33];
  int c0 = blockIdx.x * 32, r0 = blockIdx.y * 32;
  for (int i = threadIdx.y; i < 32; i += 8)
    tile[i][threadIdx.x] = in[(size_t)(r0 + i) * cols + c0 + threadIdx.x];
  __syncthreads();
  for (int i = threadIdx.y; i < 32; i += 8)
    out[(size_t)(c0 + i) * rows + r0 + threadIdx.x] = f2bf(tile[threadIdx.x][i]);
}

// ---------------- GEMM: C[M,N] = A[M,K] @ BT[N,K]^T + bias ----------------
// 4 waves (2m x 2n); wave tile = (BM/2) x (BN/2) as MI x NJ 32x32 quads.
// BIG PHASES: 8 MFMA + 8 ds_read per wave per BK=32 step at 128x128 —
// phase cost on this chip is ~1000 cyc regardless of content (measured
// rounds 10-13), so pack more work per phase. Depth-2 counted-vmcnt
// pipeline (round-12 schedule), XOR-swizzled LDS both sides.
template <int BM, int BN, int MODE>
__global__ __launch_bounds__(256) void gemm_bt(
    const unsigned short* __restrict__ A,   // [M][K] bf16
    const unsigned short* __restrict__ BT,  // [N][K] bf16
    const float* __restrict__ bias,         // [N]
    int M, int N, int K,
    unsigned short* __restrict__ outK, unsigned short* __restrict__ outQ,
    unsigned short* __restrict__ outVT, float* __restrict__ outF) {
  constexpr int MI = BM / 64;            // 32x32 row-blocks per wave
  constexpr int NJ = BN / 64;            // 32x32 col-blocks per wave
  constexpr int L = BM / 64 + BN / 64;   // own-wave gload_lds per stage
  __shared__ __align__(16) unsigned short lds_a[2][BM][32];
  __shared__ __align__(16) unsigned short lds_b[2][BN][32];
  const int tid = threadIdx.x;
  const int lane = tid & 63;
  const int w = tid >> 6;
  const int wm = w >> 1, wn = w & 1;
  const int l31 = lane & 31, hi = lane >> 5;
  const int m0 = blockIdx.y * BM, n0 = blockIdx.x * BN;

  f32x16 acc[MI][NJ];
#pragma unroll
  for (int mi = 0; mi < MI; mi++)
#pragma unroll
    for (int nj = 0; nj < NJ; nj++)
#pragma unroll
      for (int i = 0; i < 16; i++) acc[mi][nj][i] = 0.f;

  const int srow = lane >> 2;                               // 0..15 in wave band
  const int sg = ((lane & 3) ^ ((lane >> 3) & 3)) * 8;      // swizzled global k-chunk
  const int xq = (l31 >> 1) & 3;                            // read-side XOR

#define STAGE(buf, k0)                                                        \
  {                                                                           \
    _Pragma("unroll")                                                         \
    for (int rr = 0; rr < BM / 64; ++rr)                                      \
      GLOAD16(&A[(size_t)(m0 + rr * 64 + w * 16 + srow) * K + (k0) + sg],     \
              &lds_a[buf][rr * 64 + w * 16][0]);                              \
    _Pragma("unroll")                                                         \
    for (int rr = 0; rr < BN / 64; ++rr)                                      \
      GLOAD16(&BT[(size_t)(n0 + rr * 64 + w * 16 + srow) * K + (k0) + sg],    \
              &lds_b[buf][rr * 64 + w * 16][0]);                              \
  }

  const int KT = K >> 5;   // 24 for K=768
  STAGE(0, 0);
  STAGE(1, 32);

  for (int kt = 0; kt < KT; ++kt) {
    const int cur = kt & 1;
    // wait for stage kt only; stage kt+1 stays in flight (counted, not 0)
    if (kt + 1 < KT) {
      if constexpr (L == 4)      asm volatile("s_waitcnt vmcnt(4)" ::: "memory");
      else if constexpr (L == 3) asm volatile("s_waitcnt vmcnt(3)" ::: "memory");
      else                       asm volatile("s_waitcnt vmcnt(2)" ::: "memory");
    } else {
      asm volatile("s_waitcnt vmcnt(0)" ::: "memory");
    }
    __builtin_amdgcn_s_barrier();          // all waves' stage-kt loads landed
    __builtin_amdgcn_sched_barrier(0);     // pin ds_reads below the barrier

    bf16x8 aA[2][MI], aB[2][NJ];
#pragma unroll
    for (int ds = 0; ds < 2; ds++) {
      const int rc = ((ds * 2 + hi) ^ xq) * 8;   // swizzled read chunk (shorts)
#pragma unroll
      for (int mi = 0; mi < MI; mi++)
        aA[ds][mi] = *(const bf16x8*)&lds_a[cur][wm * (BM / 2) + mi * 32 + l31][rc];
#pragma unroll
      for (int nj = 0; nj < NJ; nj++)
        aB[ds][nj] = *(const bf16x8*)&lds_b[cur][wn * (BN / 2) + nj * 32 + l31][rc];
    }
#pragma unroll
    for (int ds = 0; ds < 2; ds++)
#pragma unroll
      for (int mi = 0; mi < MI; mi++)
#pragma unroll
        for (int nj = 0; nj < NJ; nj++)
          acc[mi][nj] = __builtin_amdgcn_mfma_f32_32x32x16_bf16(
              aA[ds][mi], aB[ds][nj], acc[mi][nj], 0, 0, 0);

    __builtin_amdgcn_s_barrier();          // all waves done reading buf[cur]
    if (kt + 2 < KT) STAGE(cur, (kt + 2) << 5);
  }
#undef STAGE

#pragma unroll
  for (int mi = 0; mi < MI; mi++) {
#pragma unroll
    for (int nj = 0; nj < NJ; nj++) {
#pragma unroll
      for (int r = 0; r < 16; r++) {
        int row = m0 + wm * (BM / 2) + mi * 32 + (r & 3) + 8 * (r >> 2) + 4 * hi;
        int col = n0 + wn * (BN / 2) + nj * 32 + l31;
        float v = acc[mi][nj][r] + bias[col];
        if (MODE == 0) {
          int chunk = col / DMODEL;          // 0=k, 1=q, 2=v
          int d = col - chunk * DMODEL;
          int hh = d >> 6, di = d & 63;
          int bb = row >> 11, tok = row & 2047;
          int bh = bb * NH + hh;
          if (chunk == 0)
            outK[((size_t)bh * SEQ + tok) * HD + di] = f2bf(v);
          else if (chunk == 1)
            outQ[((size_t)bh * SEQ + tok) * HD + di] = f2bf(v * 0.125f);
          else
            outVT[((size_t)bh * HD + di) * SEQ + tok] = f2bf(v);
        } else {
          outF[(size_t)row * N + col] = v;
        }
      }
    }
  }
}

// ---------------- flash attention (round-8 verified; t-major order) ----------------
// grid 1536 (64 q-tiles x 24 heads), XCD-affine; dispatch order t-MAJOR
// interleaved across heads (3 longest blocks per XCD launch first).
// Swapped QK^T (S^T = mfma(K,Q)): P lane-local -> in-register softmax,
// pack via cvt_pk + permlane32_swap (swap(X,Y) -> ret0={Xlo,Ylo}, ret1={Xhi,Yhi}).
__global__ __launch_bounds__(128) void attn_kernel(
    const unsigned short* __restrict__ qbuf,  // [BH][SEQ][HD], pre-scaled by 1/8
    const unsigned short* __restrict__ kbuf,  // [BH][SEQ][HD]
    const unsigned short* __restrict__ vT,    // [BH][HD][SEQ]
    unsigned short* __restrict__ sa) {        // [B][SEQ][DMODEL]
  __shared__ __align__(16) char smem_raw[18432];
  auto k_lds = reinterpret_cast<unsigned short (*)[72]>(smem_raw);            // [64][72]
  auto v_lds = reinterpret_cast<unsigned short (*)[72]>(smem_raw + 9216);     // [64][72]
  auto o_merge = reinterpret_cast<float (*)[32][33]>(smem_raw);               // [2][32][33] (aliases k_lds)
  auto l_merge = reinterpret_cast<float (*)[32]>(smem_raw + 9216);            // [2][32]     (aliases v_lds)

  const int tid = threadIdx.x, lane = tid & 63, w = tid >> 6;
  const int l31 = lane & 31, hi = lane >> 5;

  // XCD-affine remap: fid%8 == XCD; 3 heads/XCD; t-major longest-first
  const int fid = (int)blockIdx.y * (int)gridDim.x + (int)blockIdx.x;  // 0..1535
  const int xcd = fid & 7, slot = fid >> 3;       // slot 0..191
  const int head3 = slot % 3;
  const int t = 63 - slot / 3;                    // 32-row q-tile, longest first
  const int bh = head3 * 8 + xcd;                 // 0..23
  const int ktmax = t >> 1;                       // inclusive last 64-key tile

  const size_t qk_base = (size_t)bh * SEQ * HD;
  const size_t v_base = (size_t)bh * HD * SEQ;
  const int bb = bh / NH, h = bh - bb * NH;

  const int sr = w * 32 + (lane >> 3);
  const int sc = (lane & 7) * 8;

  {  // prologue: stage k-tile 0
    bf16x8 rk[4], rv[4];
#pragma unroll
    for (int p = 0; p < 4; p++) {
      rk[p] = *(const bf16x8*)&kbuf[qk_base + (size_t)(sr + 8 * p) * HD + sc];
      rv[p] = *(const bf16x8*)&vT[v_base + (size_t)(sr + 8 * p) * SEQ + sc];
    }
#pragma unroll
    for (int p = 0; p < 4; p++) {
      *(bf16x8*)&k_lds[sr + 8 * p][sc] = rk[p];
      *(bf16x8*)&v_lds[sr + 8 * p][sc] = rv[p];
    }
  }

  bf16x8 aq[4];
#pragma unroll
  for (int ds = 0; ds < 4; ds++)
    aq[ds] = *(const bf16x8*)&qbuf[qk_base + (size_t)(t * 32 + l31) * HD + ds * 16 + hi * 8];

  f32x16 o0, o1;
#pragma unroll
  for (int i = 0; i < 16; i++) { o0[i] = 0.f; o1[i] = 0.f; }
  float lsum = 0.f;

  __syncthreads();

  for (int kt = 0; kt <= ktmax; ++kt) {
    const bool more = (kt < ktmax);
    // ---- prefetch next tile's K/V into registers (coalesced) ----
    bf16x8 rk[4], rv[4];
    if (more) {
      const int nrow = (kt + 1) * 64;
#pragma unroll
      for (int p = 0; p < 4; p++) {
        rk[p] = *(const bf16x8*)&kbuf[qk_base + (size_t)(nrow + sr + 8 * p) * HD + sc];
        rv[p] = *(const bf16x8*)&vT[v_base + (size_t)(sr + 8 * p) * SEQ + nrow + sc];
      }
    }

    // ---- S^T[32k x 32q] = K @ Q^T (wave's 32-key window) ----
    f32x16 s;
#pragma unroll
    for (int i = 0; i < 16; i++) s[i] = 0.f;
    __builtin_amdgcn_s_setprio(1);
#pragma unroll
    for (int ds = 0; ds < 4; ds++) {
      bf16x8 bk = *(const bf16x8*)&k_lds[w * 32 + l31][ds * 16 + hi * 8];
      s = __builtin_amdgcn_mfma_f32_32x32x16_bf16(bk, aq[ds], s, 0, 0, 0);
    }
    __builtin_amdgcn_s_setprio(0);

    // ---- mask + fixed-shift exp (in registers); accumulate denominator ----
    const bool diag = (kt == ktmax);
    const int qb2 = (t & 1) * 32;
#pragma unroll
    for (int r = 0; r < 16; r++) {
      int kr = (r & 3) + 8 * (r >> 2) + 4 * hi;   // key row within wave window
      float val = s[r];
      if (diag && (w * 32 + kr > qb2 + l31)) val = -1e30f;
      float p = __expf(val);
      s[r] = p;
      lsum += p;
    }

    // ---- pack P -> PV A-fragments ----
    union { unsigned int u[4]; bf16x8 v; } f1, f2;
    {
      unsigned int A = cvtpk(s[0], s[1]), B = cvtpk(s[2], s[3]);
      unsigned int C = cvtpk(s[4], s[5]), D = cvtpk(s[6], s[7]);
      auto rAC = __builtin_amdgcn_permlane32_swap(A, C, false, false);
      auto rBD = __builtin_amdgcn_permlane32_swap(B, D, false, false);
      f1.u[0] = rAC[0]; f1.u[1] = rBD[0]; f1.u[2] = rAC[1]; f1.u[3] = rBD[1];
      unsigned int A2 = cvtpk(s[8], s[9]),   B2 = cvtpk(s[10], s[11]);
      unsigned int C2 = cvtpk(s[12], s[13]), D2 = cvtpk(s[14], s[15]);
      auto rAC2 = __builtin_amdgcn_permlane32_swap(A2, C2, false, false);
      auto rBD2 = __builtin_amdgcn_permlane32_swap(B2, D2, false, false);
      f2.u[0] = rAC2[0]; f2.u[1] = rBD2[0]; f2.u[2] = rAC2[1]; f2.u[3] = rBD2[1];
    }

    // ---- O += P @ V (two 16-k windows x two 32-d blocks) ----
    __builtin_amdgcn_s_setprio(1);
    {
      bf16x8 bv00 = *(const bf16x8*)&v_lds[l31][w * 32 + hi * 8];
      bf16x8 bv01 = *(const bf16x8*)&v_lds[32 + l31][w * 32 + hi * 8];
      o0 = __builtin_amdgcn_mfma_f32_32x32x16_bf16(f1.v, bv00, o0, 0, 0, 0);
      o1 = __builtin_amdgcn_mfma_f32_32x32x16_bf16(f1.v, bv01, o1, 0, 0, 0);
      bf16x8 bv10 = *(const bf16x8*)&v_lds[l31][w * 32 + 16 + hi * 8];
      bf16x8 bv11 = *(const bf16x8*)&v_lds[32 + l31][w * 32 + 16 + hi * 8];
      o0 = __builtin_amdgcn_mfma_f32_32x32x16_bf16(f2.v, bv10, o0, 0, 0, 0);
      o1 = __builtin_amdgcn_mfma_f32_32x32x16_bf16(f2.v, bv11, o1, 0, 0, 0);
    }
    __builtin_amdgcn_s_setprio(0);

    // ---- stage prefetched tile ----
    if (more) {
      __syncthreads();
#pragma unroll
      for (int p = 0; p < 4; p++) {
        *(bf16x8*)&k_lds[sr + 8 * p][sc] = rk[p];
        *(bf16x8*)&v_lds[sr + 8 * p][sc] = rv[p];
      }
      __syncthreads();
    }
  }

  // ---- merge wave partials (LDS aliased over dead k/v tiles) ----
  __syncthreads();
  {
    float ltot = lsum + __shfl_xor(lsum, 32);
    if (hi == 0) l_merge[w][l31] = ltot;
    f32x16 osend = w ? o0 : o1;
#pragma unroll
    for (int r = 0; r < 16; r++) {
      int ql = (r & 3) + 8 * (r >> 2) + 4 * hi;
      o_merge[w][ql][l31] = osend[r];
    }
    __syncthreads();
    f32x16 okeep = w ? o1 : o0;
#pragma unroll
    for (int r = 0; r < 16; r++) {
      int ql = (r & 3) + 8 * (r >> 2) + 4 * hi;
      float ot = okeep[r] + o_merge[1 - w][ql][l31];
      float lt = l_merge[0][ql] + l_merge[1][ql];
      sa[((size_t)bb * SEQ + t * 32 + ql) * DMODEL + h * HD + w * 32 + l31] = f2bf(ot / lt);
    }
  }
}

// ---------------- launch ----------------

extern "C" void kernel_launch(void* const* d_in, const int* in_sizes, int n_in,
                              void* d_out, int out_size, void* d_ws, size_t ws_size,
                              hipStream_t stream) {
  const float* x     = (const float*)d_in[0];
  const float* Wkqv  = (const float*)d_in[1];
  const float* bkqv  = (const float*)d_in[2];
  const float* Wproj = (const float*)d_in[3];
  const float* bproj = (const float*)d_in[4];
  float* out = (float*)d_out;

  char* ws = (char*)d_ws;
  unsigned short* x_bf   = (unsigned short*)(ws + 0);
  unsigned short* wkqvT  = (unsigned short*)(ws + 6291456);
  unsigned short* wprojT = (unsigned short*)(ws + 9830400);
  unsigned short* qb     = (unsigned short*)(ws + 11010048);
  unsigned short* kb     = (unsigned short*)(ws + 17301504);
  unsigned short* vT     = (unsigned short*)(ws + 23592960);
  unsigned short* sa     = (unsigned short*)(ws + 29884416);

  cvt_f32_bf16<<<(M_TOK * DMODEL / 4 + 255) / 256, 256, 0, stream>>>(x, x_bf, M_TOK * DMODEL / 4);
  transpose_cvt<<<dim3(N_KQV / 32, DMODEL / 32), dim3(32, 8), 0, stream>>>(Wkqv, wkqvT, DMODEL, N_KQV);
  transpose_cvt<<<dim3(DMODEL / 32, DMODEL / 32), dim3(32, 8), 0, stream>>>(Wproj, wprojT, DMODEL, DMODEL);

  // GEMM1: 128x128 tiles -> 576 blocks, 8 MFMA/wave/phase
  gemm_bt<128, 128, 0><<<dim3(N_KQV / 128, M_TOK / 128), 256, 0, stream>>>(
      x_bf, wkqvT, bkqv, M_TOK, N_KQV, DMODEL, kb, qb, vT, nullptr);

  attn_kernel<<<dim3(64, BATCH * NH), 128, 0, stream>>>(qb, kb, vT, sa);

  // GEMM2: 64x64 tiles -> 768 blocks (round-12 config)
  gemm_bt<64, 64, 1><<<dim3(DMODEL / 64, M_TOK / 64), 256, 0, stream>>>(
      sa, wprojT, bproj, M_TOK, DMODEL, DMODEL, nullptr, nullptr, nullptr, out);
}

// Round 15
// 102.961 us; speedup vs baseline: 1.0949x; 1.0476x over previous
//
#include <hip/hip_runtime.h>

typedef __attribute__((ext_vector_type(8))) short bf16x8;
typedef __attribute__((ext_vector_type(4))) float f32x4;
typedef __attribute__((ext_vector_type(16))) float f32x16;

#define BATCH 2
#define SEQ 2048
#define DMODEL 768
#define NH 12
#define HD 64
#define M_TOK (BATCH * SEQ)   /* 4096 */
#define N_KQV (3 * DMODEL)    /* 2304 */

#define GLOAD16(gsrc, ldst) __builtin_amdgcn_global_load_lds( \
    (const __attribute__((address_space(1))) unsigned int*)(const void*)(gsrc), \
    (__attribute__((address_space(3))) unsigned int*)(void*)(ldst), 16, 0, 0)

__device__ __forceinline__ unsigned short f2bf(float f) {
  unsigned int u = __float_as_uint(f);
  u += 0x7FFFu + ((u >> 16) & 1u);
  return (unsigned short)(u >> 16);
}

__device__ __forceinline__ unsigned int cvtpk(float lo, float hi) {
  unsigned int r;
  asm("v_cvt_pk_bf16_f32 %0, %1, %2" : "=v"(r) : "v"(lo), "v"(hi));
  return r;
}

// ---------------- merged prep kernel ----------------
// job A: x f32->bf16 (blocks [0, NB_CVT))
// job B: Wkqv transpose-cvt (blocks [NB_CVT, NB_CVT+NB_T1))
// job C: Wproj transpose-cvt (rest)
#define NB_CVT 3072                       /* 4096*768/4/256 */
#define NB_T1 (72 * 24)                   /* 2304/32 x 768/32 */
#define NB_T2 (24 * 24)                   /* 768/32 x 768/32 */

__global__ __launch_bounds__(256) void prep_kernel(
    const float* __restrict__ x, unsigned short* __restrict__ x_bf,
    const float* __restrict__ Wkqv, unsigned short* __restrict__ wkqvT,
    const float* __restrict__ Wproj, unsigned short* __restrict__ wprojT) {
  const int b = blockIdx.x;
  if (b < NB_CVT) {
    int i = b * 256 + threadIdx.x;
    float4 v = reinterpret_cast<const float4*>(x)[i];
    unsigned long long p = (unsigned long long)f2bf(v.x)
                         | ((unsigned long long)f2bf(v.y) << 16)
                         | ((unsigned long long)f2bf(v.z) << 32)
                         | ((unsigned long long)f2bf(v.w) << 48);
    reinterpret_cast<unsigned long long*>(x_bf)[i] = p;
    return;
  }
  // transpose jobs: out[c][r] = bf16(in[r][c])
  __shared__ float tile[32][33];
  const float* in;
  unsigned short* out;
  int rows, cols, bx, by;
  if (b < NB_CVT + NB_T1) {
    int j = b - NB_CVT;
    in = Wkqv; out = wkqvT; rows = DMODEL; cols = N_KQV;
    bx = j % 72; by = j / 72;
  } else {
    int j = b - NB_CVT - NB_T1;
    in = Wproj; out = wprojT; rows = DMODEL; cols = DMODEL;
    bx = j % 24; by = j / 24;
  }
  const int tx = threadIdx.x & 31, ty = threadIdx.x >> 5;  // 32 x 8
  int c0 = bx * 32, r0 = by * 32;
  for (int i = ty; i < 32; i += 8)
    tile[i][tx] = in[(size_t)(r0 + i) * cols + c0 + tx];
  __syncthreads();
  for (int i = ty; i < 32; i += 8)
    out[(size_t)(c0 + i) * rows + r0 + tx] = f2bf(tile[tx][i]);
}

// ---------------- GEMM: C[M,N] = A[M,K] @ BT[N,K]^T + bias ----------------
// 4 waves (2m x 2n); wave tile = (BM/2) x (BN/2) as MI x NJ 32x32 quads.
// SINGLE barrier per phase: 3 LDS stage buffers give 2-phase WAR
// separation, so the read-protect barrier is unnecessary. Counted vmcnt
// (never 0 in-loop); prefetch issue->wait slack ~2 phases >> load latency.
// XOR-swizzled LDS both sides (round-11, conflict-verified).
template <int BM, int BN, int MODE>
__global__ __launch_bounds__(256) void gemm_bt(
    const unsigned short* __restrict__ A,   // [M][K] bf16
    const unsigned short* __restrict__ BT,  // [N][K] bf16
    const float* __restrict__ bias,         // [N]
    int M, int N, int K,
    unsigned short* __restrict__ outK, unsigned short* __restrict__ outQ,
    unsigned short* __restrict__ outVT, float* __restrict__ outF) {
  constexpr int MI = BM / 64;            // 32x32 row-blocks per wave
  constexpr int NJ = BN / 64;            // 32x32 col-blocks per wave
  constexpr int L = BM / 64 + BN / 64;   // own-wave gload_lds per stage
  __shared__ __align__(16) unsigned short lds_a[3][BM][32];
  __shared__ __align__(16) unsigned short lds_b[3][BN][32];
  const int tid = threadIdx.x;
  const int lane = tid & 63;
  const int w = tid >> 6;
  const int wm = w >> 1, wn = w & 1;
  const int l31 = lane & 31, hi = lane >> 5;
  const int m0 = blockIdx.y * BM, n0 = blockIdx.x * BN;

  f32x16 acc[MI][NJ];
#pragma unroll
  for (int mi = 0; mi < MI; mi++)
#pragma unroll
    for (int nj = 0; nj < NJ; nj++)
#pragma unroll
      for (int i = 0; i < 16; i++) acc[mi][nj][i] = 0.f;

  const int srow = lane >> 2;                               // 0..15 in wave band
  const int sg = ((lane & 3) ^ ((lane >> 3) & 3)) * 8;      // swizzled global k-chunk
  const int xq = (l31 >> 1) & 3;                            // read-side XOR

#define STAGE(buf, k0)                                                        \
  {                                                                           \
    _Pragma("unroll")                                                         \
    for (int rr = 0; rr < BM / 64; ++rr)                                      \
      GLOAD16(&A[(size_t)(m0 + rr * 64 + w * 16 + srow) * K + (k0) + sg],     \
              &lds_a[buf][rr * 64 + w * 16][0]);                              \
    _Pragma("unroll")                                                         \
    for (int rr = 0; rr < BN / 64; ++rr)                                      \
      GLOAD16(&BT[(size_t)(n0 + rr * 64 + w * 16 + srow) * K + (k0) + sg],    \
              &lds_b[buf][rr * 64 + w * 16][0]);                              \
  }

  const int KT = K >> 5;   // 24 for K=768
  STAGE(0, 0);
  STAGE(1, 32);

  int cur = 0;
  for (int kt = 0; kt < KT; ++kt) {
    // wait for stage kt; stage kt+1 stays in flight (counted, not 0)
    if (kt + 1 < KT) {
      if constexpr (L == 4)      asm volatile("s_waitcnt vmcnt(4)" ::: "memory");
      else if constexpr (L == 3) asm volatile("s_waitcnt vmcnt(3)" ::: "memory");
      else                       asm volatile("s_waitcnt vmcnt(2)" ::: "memory");
    } else {
      asm volatile("s_waitcnt vmcnt(0)" ::: "memory");
    }
    __builtin_amdgcn_s_barrier();          // ONLY barrier this phase
    __builtin_amdgcn_sched_barrier(0);     // pin reads AND prefetch below it

    bf16x8 aA[2][MI], aB[2][NJ];
#pragma unroll
    for (int ds = 0; ds < 2; ds++) {
      const int rc = ((ds * 2 + hi) ^ xq) * 8;   // swizzled read chunk (shorts)
#pragma unroll
      for (int mi = 0; mi < MI; mi++)
        aA[ds][mi] = *(const bf16x8*)&lds_a[cur][wm * (BM / 2) + mi * 32 + l31][rc];
#pragma unroll
      for (int nj = 0; nj < NJ; nj++)
        aB[ds][nj] = *(const bf16x8*)&lds_b[cur][wn * (BN / 2) + nj * 32 + l31][rc];
    }
#pragma unroll
    for (int ds = 0; ds < 2; ds++)
#pragma unroll
      for (int mi = 0; mi < MI; mi++)
#pragma unroll
        for (int nj = 0; nj < NJ; nj++)
          acc[mi][nj] = __builtin_amdgcn_mfma_f32_32x32x16_bf16(
              aA[ds][mi], aB[ds][nj], acc[mi][nj], 0, 0, 0);

    // prefetch kt+2 into buf[(kt+2)%3] = buf[(kt-1)%3]: its readers all
    // exited at this phase's barrier -> WAR-safe without a second barrier.
    if (kt + 2 < KT) {
      const int nb = (cur + 2 >= 3) ? cur - 1 : cur + 2;
      STAGE(nb, (kt + 2) << 5);
    }
    cur = (cur == 2) ? 0 : cur + 1;
  }
#undef STAGE

#pragma unroll
  for (int mi = 0; mi < MI; mi++) {
#pragma unroll
    for (int nj = 0; nj < NJ; nj++) {
#pragma unroll
      for (int r = 0; r < 16; r++) {
        int row = m0 + wm * (BM / 2) + mi * 32 + (r & 3) + 8 * (r >> 2) + 4 * hi;
        int col = n0 + wn * (BN / 2) + nj * 32 + l31;
        float v = acc[mi][nj][r] + bias[col];
        if (MODE == 0) {
          int chunk = col / DMODEL;          // 0=k, 1=q, 2=v
          int d = col - chunk * DMODEL;
          int hh = d >> 6, di = d & 63;
          int bb = row >> 11, tok = row & 2047;
          int bh = bb * NH + hh;
          if (chunk == 0)
            outK[((size_t)bh * SEQ + tok) * HD + di] = f2bf(v);
          else if (chunk == 1)
            outQ[((size_t)bh * SEQ + tok) * HD + di] = f2bf(v * 0.125f);
          else
            outVT[((size_t)bh * HD + di) * SEQ + tok] = f2bf(v);
        } else {
          outF[(size_t)row * N + col] = v;
        }
      }
    }
  }
}

// ---------------- flash attention (round-8 verified; t-major order) ----------------
__global__ __launch_bounds__(128) void attn_kernel(
    const unsigned short* __restrict__ qbuf,  // [BH][SEQ][HD], pre-scaled by 1/8
    const unsigned short* __restrict__ kbuf,  // [BH][SEQ][HD]
    const unsigned short* __restrict__ vT,    // [BH][HD][SEQ]
    unsigned short* __restrict__ sa) {        // [B][SEQ][DMODEL]
  __shared__ __align__(16) char smem_raw[18432];
  auto k_lds = reinterpret_cast<unsigned short (*)[72]>(smem_raw);            // [64][72]
  auto v_lds = reinterpret_cast<unsigned short (*)[72]>(smem_raw + 9216);     // [64][72]
  auto o_merge = reinterpret_cast<float (*)[32][33]>(smem_raw);               // [2][32][33]
  auto l_merge = reinterpret_cast<float (*)[32]>(smem_raw + 9216);            // [2][32]

  const int tid = threadIdx.x, lane = tid & 63, w = tid >> 6;
  const int l31 = lane & 31, hi = lane >> 5;

  // XCD-affine remap: fid%8 == XCD; 3 heads/XCD; t-major longest-first
  const int fid = (int)blockIdx.y * (int)gridDim.x + (int)blockIdx.x;  // 0..1535
  const int xcd = fid & 7, slot = fid >> 3;       // slot 0..191
  const int head3 = slot % 3;
  const int t = 63 - slot / 3;                    // 32-row q-tile, longest first
  const int bh = head3 * 8 + xcd;                 // 0..23
  const int ktmax = t >> 1;                       // inclusive last 64-key tile

  const size_t qk_base = (size_t)bh * SEQ * HD;
  const size_t v_base = (size_t)bh * HD * SEQ;
  const int bb = bh / NH, h = bh - bb * NH;

  const int sr = w * 32 + (lane >> 3);
  const int sc = (lane & 7) * 8;

  {  // prologue: stage k-tile 0
    bf16x8 rk[4], rv[4];
#pragma unroll
    for (int p = 0; p < 4; p++) {
      rk[p] = *(const bf16x8*)&kbuf[qk_base + (size_t)(sr + 8 * p) * HD + sc];
      rv[p] = *(const bf16x8*)&vT[v_base + (size_t)(sr + 8 * p) * SEQ + sc];
    }
#pragma unroll
    for (int p = 0; p < 4; p++) {
      *(bf16x8*)&k_lds[sr + 8 * p][sc] = rk[p];
      *(bf16x8*)&v_lds[sr + 8 * p][sc] = rv[p];
    }
  }

  bf16x8 aq[4];
#pragma unroll
  for (int ds = 0; ds < 4; ds++)
    aq[ds] = *(const bf16x8*)&qbuf[qk_base + (size_t)(t * 32 + l31) * HD + ds * 16 + hi * 8];

  f32x16 o0, o1;
#pragma unroll
  for (int i = 0; i < 16; i++) { o0[i] = 0.f; o1[i] = 0.f; }
  float lsum = 0.f;

  __syncthreads();

  for (int kt = 0; kt <= ktmax; ++kt) {
    const bool more = (kt < ktmax);
    bf16x8 rk[4], rv[4];
    if (more) {
      const int nrow = (kt + 1) * 64;
#pragma unroll
      for (int p = 0; p < 4; p++) {
        rk[p] = *(const bf16x8*)&kbuf[qk_base + (size_t)(nrow + sr + 8 * p) * HD + sc];
        rv[p] = *(const bf16x8*)&vT[v_base + (size_t)(sr + 8 * p) * SEQ + nrow + sc];
      }
    }

    f32x16 s;
#pragma unroll
    for (int i = 0; i < 16; i++) s[i] = 0.f;
    __builtin_amdgcn_s_setprio(1);
#pragma unroll
    for (int ds = 0; ds < 4; ds++) {
      bf16x8 bk = *(const bf16x8*)&k_lds[w * 32 + l31][ds * 16 + hi * 8];
      s = __builtin_amdgcn_mfma_f32_32x32x16_bf16(bk, aq[ds], s, 0, 0, 0);
    }
    __builtin_amdgcn_s_setprio(0);

    const bool diag = (kt == ktmax);
    const int qb2 = (t & 1) * 32;
#pragma unroll
    for (int r = 0; r < 16; r++) {
      int kr = (r & 3) + 8 * (r >> 2) + 4 * hi;
      float val = s[r];
      if (diag && (w * 32 + kr > qb2 + l31)) val = -1e30f;
      float p = __expf(val);
      s[r] = p;
      lsum += p;
    }

    union { unsigned int u[4]; bf16x8 v; } f1, f2;
    {
      unsigned int A = cvtpk(s[0], s[1]), B = cvtpk(s[2], s[3]);
      unsigned int C = cvtpk(s[4], s[5]), D = cvtpk(s[6], s[7]);
      auto rAC = __builtin_amdgcn_permlane32_swap(A, C, false, false);
      auto rBD = __builtin_amdgcn_permlane32_swap(B, D, false, false);
      f1.u[0] = rAC[0]; f1.u[1] = rBD[0]; f1.u[2] = rAC[1]; f1.u[3] = rBD[1];
      unsigned int A2 = cvtpk(s[8], s[9]),   B2 = cvtpk(s[10], s[11]);
      unsigned int C2 = cvtpk(s[12], s[13]), D2 = cvtpk(s[14], s[15]);
      auto rAC2 = __builtin_amdgcn_permlane32_swap(A2, C2, false, false);
      auto rBD2 = __builtin_amdgcn_permlane32_swap(B2, D2, false, false);
      f2.u[0] = rAC2[0]; f2.u[1] = rBD2[0]; f2.u[2] = rAC2[1]; f2.u[3] = rBD2[1];
    }

    __builtin_amdgcn_s_setprio(1);
    {
      bf16x8 bv00 = *(const bf16x8*)&v_lds[l31][w * 32 + hi * 8];
      bf16x8 bv01 = *(const bf16x8*)&v_lds[32 + l31][w * 32 + hi * 8];
      o0 = __builtin_amdgcn_mfma_f32_32x32x16_bf16(f1.v, bv00, o0, 0, 0, 0);
      o1 = __builtin_amdgcn_mfma_f32_32x32x16_bf16(f1.v, bv01, o1, 0, 0, 0);
      bf16x8 bv10 = *(const bf16x8*)&v_lds[l31][w * 32 + 16 + hi * 8];
      bf16x8 bv11 = *(const bf16x8*)&v_lds[32 + l31][w * 32 + 16 + hi * 8];
      o0 = __builtin_amdgcn_mfma_f32_32x32x16_bf16(f2.v, bv10, o0, 0, 0, 0);
      o1 = __builtin_amdgcn_mfma_f32_32x32x16_bf16(f2.v, bv11, o1, 0, 0, 0);
    }
    __builtin_amdgcn_s_setprio(0);

    if (more) {
      __syncthreads();
#pragma unroll
      for (int p = 0; p < 4; p++) {
        *(bf16x8*)&k_lds[sr + 8 * p][sc] = rk[p];
        *(bf16x8*)&v_lds[sr + 8 * p][sc] = rv[p];
      }
      __syncthreads();
    }
  }

  __syncthreads();
  {
    float ltot = lsum + __shfl_xor(lsum, 32);
    if (hi == 0) l_merge[w][l31] = ltot;
    f32x16 osend = w ? o0 : o1;
#pragma unroll
    for (int r = 0; r < 16; r++) {
      int ql = (r & 3) + 8 * (r >> 2) + 4 * hi;
      o_merge[w][ql][l31] = osend[r];
    }
    __syncthreads();
    f32x16 okeep = w ? o1 : o0;
#pragma unroll
    for (int r = 0; r < 16; r++) {
      int ql = (r & 3) + 8 * (r >> 2) + 4 * hi;
      float ot = okeep[r] + o_merge[1 - w][ql][l31];
      float lt = l_merge[0][ql] + l_merge[1][ql];
      sa[((size_t)bb * SEQ + t * 32 + ql) * DMODEL + h * HD + w * 32 + l31] = f2bf(ot / lt);
    }
  }
}

// ---------------- launch ----------------

extern "C" void kernel_launch(void* const* d_in, const int* in_sizes, int n_in,
                              void* d_out, int out_size, void* d_ws, size_t ws_size,
                              hipStream_t stream) {
  const float* x     = (const float*)d_in[0];
  const float* Wkqv  = (const float*)d_in[1];
  const float* bkqv  = (const float*)d_in[2];
  const float* Wproj = (const float*)d_in[3];
  const float* bproj = (const float*)d_in[4];
  float* out = (float*)d_out;

  char* ws = (char*)d_ws;
  unsigned short* x_bf   = (unsigned short*)(ws + 0);
  unsigned short* wkqvT  = (unsigned short*)(ws + 6291456);
  unsigned short* wprojT = (unsigned short*)(ws + 9830400);
  unsigned short* qb     = (unsigned short*)(ws + 11010048);
  unsigned short* kb     = (unsigned short*)(ws + 17301504);
  unsigned short* vT     = (unsigned short*)(ws + 23592960);
  unsigned short* sa     = (unsigned short*)(ws + 29884416);

  prep_kernel<<<NB_CVT + NB_T1 + NB_T2, 256, 0, stream>>>(
      x, x_bf, Wkqv, wkqvT, Wproj, wprojT);

  // GEMM1: 128x128 tiles -> 576 blocks, single-barrier 3-buffer pipeline
  gemm_bt<128, 128, 0><<<dim3(N_KQV / 128, M_TOK / 128), 256, 0, stream>>>(
      x_bf, wkqvT, bkqv, M_TOK, N_KQV, DMODEL, kb, qb, vT, nullptr);

  attn_kernel<<<dim3(64, BATCH * NH), 128, 0, stream>>>(qb, kb, vT, sa);

  // GEMM2: 64x64 tiles -> 768 blocks, same schedule
  gemm_bt<64, 64, 1><<<dim3(DMODEL / 64, M_TOK / 64), 256, 0, stream>>>(
      sa, wprojT, bproj, M_TOK, DMODEL, DMODEL, nullptr, nullptr, nullptr, out);
}

// Round 16
// 102.252 us; speedup vs baseline: 1.1025x; 1.0069x over previous
//
#include <hip/hip_runtime.h>

typedef __attribute__((ext_vector_type(8))) short bf16x8;
typedef __attribute__((ext_vector_type(4))) float f32x4;
typedef __attribute__((ext_vector_type(16))) float f32x16;

#define BATCH 2
#define SEQ 2048
#define DMODEL 768
#define NH 12
#define HD 64
#define M_TOK (BATCH * SEQ)   /* 4096 */
#define N_KQV (3 * DMODEL)    /* 2304 */

#define GLOAD16(gsrc, ldst) __builtin_amdgcn_global_load_lds( \
    (const __attribute__((address_space(1))) unsigned int*)(const void*)(gsrc), \
    (__attribute__((address_space(3))) unsigned int*)(void*)(ldst), 16, 0, 0)

__device__ __forceinline__ unsigned short f2bf(float f) {
  unsigned int u = __float_as_uint(f);
  u += 0x7FFFu + ((u >> 16) & 1u);
  return (unsigned short)(u >> 16);
}

__device__ __forceinline__ unsigned int cvtpk(float lo, float hi) {
  unsigned int r;
  asm("v_cvt_pk_bf16_f32 %0, %1, %2" : "=v"(r) : "v"(lo), "v"(hi));
  return r;
}

// ---------------- merged prep kernel ----------------
#define NB_CVT 3072                       /* 4096*768/4/256 */
#define NB_T1 (72 * 24)                   /* 2304/32 x 768/32 */
#define NB_T2 (24 * 24)                   /* 768/32 x 768/32 */

__global__ __launch_bounds__(256) void prep_kernel(
    const float* __restrict__ x, unsigned short* __restrict__ x_bf,
    const float* __restrict__ Wkqv, unsigned short* __restrict__ wkqvT,
    const float* __restrict__ Wproj, unsigned short* __restrict__ wprojT) {
  const int b = blockIdx.x;
  if (b < NB_CVT) {
    int i = b * 256 + threadIdx.x;
    float4 v = reinterpret_cast<const float4*>(x)[i];
    unsigned long long p = (unsigned long long)f2bf(v.x)
                         | ((unsigned long long)f2bf(v.y) << 16)
                         | ((unsigned long long)f2bf(v.z) << 32)
                         | ((unsigned long long)f2bf(v.w) << 48);
    reinterpret_cast<unsigned long long*>(x_bf)[i] = p;
    return;
  }
  __shared__ float tile[32][33];
  const float* in;
  unsigned short* out;
  int rows, cols, bx, by;
  if (b < NB_CVT + NB_T1) {
    int j = b - NB_CVT;
    in = Wkqv; out = wkqvT; rows = DMODEL; cols = N_KQV;
    bx = j % 72; by = j / 72;
  } else {
    int j = b - NB_CVT - NB_T1;
    in = Wproj; out = wprojT; rows = DMODEL; cols = DMODEL;
    bx = j % 24; by = j / 24;
  }
  const int tx = threadIdx.x & 31, ty = threadIdx.x >> 5;  // 32 x 8
  int c0 = bx * 32, r0 = by * 32;
  for (int i = ty; i < 32; i += 8)
    tile[i][tx] = in[(size_t)(r0 + i) * cols + c0 + tx];
  __syncthreads();
  for (int i = ty; i < 32; i += 8)
    out[(size_t)(c0 + i) * rows + r0 + tx] = f2bf(tile[tx][i]);
}

// ---------------- GEMM1: 8-WAVE 128x128 ----------------
// 512 threads = 8 waves (4m x 2n), wave tile 32x64: 6 ds_read + 4 MFMA
// per wave-phase — HALF the per-wave work of the 4-wave version at 2x
// the waves/CU (static 18/CU): latency hiding via TLP, the one variable
// rounds 10-15 never changed. Single-barrier 3-buffer counted-vmcnt
// schedule (round-15), XOR-swizzled LDS both sides.
__global__ __launch_bounds__(512) void gemm1_8w(
    const unsigned short* __restrict__ A,   // [M][K] bf16, M=4096 K=768
    const unsigned short* __restrict__ BT,  // [N][K] bf16, N=2304
    const float* __restrict__ bias,
    unsigned short* __restrict__ outK, unsigned short* __restrict__ outQ,
    unsigned short* __restrict__ outVT) {
  constexpr int K = DMODEL;
  __shared__ __align__(16) unsigned short lds_a[3][128][32];
  __shared__ __align__(16) unsigned short lds_b[3][128][32];
  const int tid = threadIdx.x;
  const int lane = tid & 63;
  const int w = tid >> 6;                  // 0..7
  const int wr = (w & 3) * 32;             // wave row base in tile
  const int wc = (w >> 2) * 64;            // wave col base in tile
  const int l31 = lane & 31, hi = lane >> 5;
  const int m0 = blockIdx.y * 128, n0 = blockIdx.x * 128;

  f32x16 acc[2];
#pragma unroll
  for (int nj = 0; nj < 2; nj++)
#pragma unroll
    for (int i = 0; i < 16; i++) acc[nj][i] = 0.f;

  const int srow = lane >> 2;                               // 0..15
  const int sg = ((lane & 3) ^ ((lane >> 3) & 3)) * 8;      // swizzled global k-chunk
  const int xq = (l31 >> 1) & 3;                            // read-side XOR

  // wave w<4 stages A rows [w*32, w*32+32); w>=4 stages B rows [(w-4)*32, +32)
#define STAGE(buf, k0)                                                         \
  {                                                                            \
    if (w < 4) {                                                               \
      GLOAD16(&A[(size_t)(m0 + w * 32 + srow) * K + (k0) + sg],                \
              &lds_a[buf][w * 32][0]);                                         \
      GLOAD16(&A[(size_t)(m0 + w * 32 + 16 + srow) * K + (k0) + sg],           \
              &lds_a[buf][w * 32 + 16][0]);                                    \
    } else {                                                                   \
      GLOAD16(&BT[(size_t)(n0 + (w - 4) * 32 + srow) * K + (k0) + sg],         \
              &lds_b[buf][(w - 4) * 32][0]);                                   \
      GLOAD16(&BT[(size_t)(n0 + (w - 4) * 32 + 16 + srow) * K + (k0) + sg],    \
              &lds_b[buf][(w - 4) * 32 + 16][0]);                              \
    }                                                                          \
  }

  const int KT = K >> 5;   // 24
  STAGE(0, 0);
  STAGE(1, 32);

  int cur = 0;
  for (int kt = 0; kt < KT; ++kt) {
    // wait for stage kt (own-wave L=2); stage kt+1 stays in flight
    if (kt + 1 < KT) asm volatile("s_waitcnt vmcnt(2)" ::: "memory");
    else             asm volatile("s_waitcnt vmcnt(0)" ::: "memory");
    __builtin_amdgcn_s_barrier();
    __builtin_amdgcn_sched_barrier(0);

    bf16x8 aA[2], aB[2][2];
#pragma unroll
    for (int ds = 0; ds < 2; ds++) {
      const int rc = ((ds * 2 + hi) ^ xq) * 8;
      aA[ds] = *(const bf16x8*)&lds_a[cur][wr + l31][rc];
#pragma unroll
      for (int nj = 0; nj < 2; nj++)
        aB[ds][nj] = *(const bf16x8*)&lds_b[cur][wc + nj * 32 + l31][rc];
    }
#pragma unroll
    for (int ds = 0; ds < 2; ds++)
#pragma unroll
      for (int nj = 0; nj < 2; nj++)
        acc[nj] = __builtin_amdgcn_mfma_f32_32x32x16_bf16(aA[ds], aB[ds][nj], acc[nj], 0, 0, 0);

    // prefetch kt+2 into buf[(kt-1)%3]; readers exited at this barrier
    if (kt + 2 < KT) {
      const int nb = (cur + 2 >= 3) ? cur - 1 : cur + 2;
      STAGE(nb, (kt + 2) << 5);
    }
    cur = (cur == 2) ? 0 : cur + 1;
  }
#undef STAGE

#pragma unroll
  for (int nj = 0; nj < 2; nj++) {
#pragma unroll
    for (int r = 0; r < 16; r++) {
      int row = m0 + wr + (r & 3) + 8 * (r >> 2) + 4 * hi;
      int col = n0 + wc + nj * 32 + l31;
      float v = acc[nj][r] + bias[col];
      int chunk = col / DMODEL;          // 0=k, 1=q, 2=v
      int d = col - chunk * DMODEL;
      int hh = d >> 6, di = d & 63;
      int bb = row >> 11, tok = row & 2047;
      int bh = bb * NH + hh;
      if (chunk == 0)
        outK[((size_t)bh * SEQ + tok) * HD + di] = f2bf(v);
      else if (chunk == 1)
        outQ[((size_t)bh * SEQ + tok) * HD + di] = f2bf(v * 0.125f);
      else
        outVT[((size_t)bh * HD + di) * SEQ + tok] = f2bf(v);
    }
  }
}

// ---------------- GEMM2 (4-wave, round-15 schedule, unchanged) ----------------
template <int BM, int BN>
__global__ __launch_bounds__(256) void gemm_bt(
    const unsigned short* __restrict__ A,
    const unsigned short* __restrict__ BT,
    const float* __restrict__ bias,
    int M, int N, int K,
    float* __restrict__ outF) {
  constexpr int MI = BM / 64;
  constexpr int NJ = BN / 64;
  constexpr int L = BM / 64 + BN / 64;
  __shared__ __align__(16) unsigned short lds_a[3][BM][32];
  __shared__ __align__(16) unsigned short lds_b[3][BN][32];
  const int tid = threadIdx.x;
  const int lane = tid & 63;
  const int w = tid >> 6;
  const int wm = w >> 1, wn = w & 1;
  const int l31 = lane & 31, hi = lane >> 5;
  const int m0 = blockIdx.y * BM, n0 = blockIdx.x * BN;

  f32x16 acc[MI][NJ];
#pragma unroll
  for (int mi = 0; mi < MI; mi++)
#pragma unroll
    for (int nj = 0; nj < NJ; nj++)
#pragma unroll
      for (int i = 0; i < 16; i++) acc[mi][nj][i] = 0.f;

  const int srow = lane >> 2;
  const int sg = ((lane & 3) ^ ((lane >> 3) & 3)) * 8;
  const int xq = (l31 >> 1) & 3;

#define STAGE(buf, k0)                                                        \
  {                                                                           \
    _Pragma("unroll")                                                         \
    for (int rr = 0; rr < BM / 64; ++rr)                                      \
      GLOAD16(&A[(size_t)(m0 + rr * 64 + w * 16 + srow) * K + (k0) + sg],     \
              &lds_a[buf][rr * 64 + w * 16][0]);                              \
    _Pragma("unroll")                                                         \
    for (int rr = 0; rr < BN / 64; ++rr)                                      \
      GLOAD16(&BT[(size_t)(n0 + rr * 64 + w * 16 + srow) * K + (k0) + sg],    \
              &lds_b[buf][rr * 64 + w * 16][0]);                              \
  }

  const int KT = K >> 5;
  STAGE(0, 0);
  STAGE(1, 32);

  int cur = 0;
  for (int kt = 0; kt < KT; ++kt) {
    if (kt + 1 < KT) {
      if constexpr (L == 4)      asm volatile("s_waitcnt vmcnt(4)" ::: "memory");
      else if constexpr (L == 3) asm volatile("s_waitcnt vmcnt(3)" ::: "memory");
      else                       asm volatile("s_waitcnt vmcnt(2)" ::: "memory");
    } else {
      asm volatile("s_waitcnt vmcnt(0)" ::: "memory");
    }
    __builtin_amdgcn_s_barrier();
    __builtin_amdgcn_sched_barrier(0);

    bf16x8 aA[2][MI], aB[2][NJ];
#pragma unroll
    for (int ds = 0; ds < 2; ds++) {
      const int rc = ((ds * 2 + hi) ^ xq) * 8;
#pragma unroll
      for (int mi = 0; mi < MI; mi++)
        aA[ds][mi] = *(const bf16x8*)&lds_a[cur][wm * (BM / 2) + mi * 32 + l31][rc];
#pragma unroll
      for (int nj = 0; nj < NJ; nj++)
        aB[ds][nj] = *(const bf16x8*)&lds_b[cur][wn * (BN / 2) + nj * 32 + l31][rc];
    }
#pragma unroll
    for (int ds = 0; ds < 2; ds++)
#pragma unroll
      for (int mi = 0; mi < MI; mi++)
#pragma unroll
        for (int nj = 0; nj < NJ; nj++)
          acc[mi][nj] = __builtin_amdgcn_mfma_f32_32x32x16_bf16(
              aA[ds][mi], aB[ds][nj], acc[mi][nj], 0, 0, 0);

    if (kt + 2 < KT) {
      const int nb = (cur + 2 >= 3) ? cur - 1 : cur + 2;
      STAGE(nb, (kt + 2) << 5);
    }
    cur = (cur == 2) ? 0 : cur + 1;
  }
#undef STAGE

#pragma unroll
  for (int mi = 0; mi < MI; mi++) {
#pragma unroll
    for (int nj = 0; nj < NJ; nj++) {
#pragma unroll
      for (int r = 0; r < 16; r++) {
        int row = m0 + wm * (BM / 2) + mi * 32 + (r & 3) + 8 * (r >> 2) + 4 * hi;
        int col = n0 + wn * (BN / 2) + nj * 32 + l31;
        outF[(size_t)row * N + col] = acc[mi][nj][r] + bias[col];
      }
    }
  }
}

// ---------------- flash attention (round-8 verified; t-major order) ----------------
__global__ __launch_bounds__(128) void attn_kernel(
    const unsigned short* __restrict__ qbuf,  // [BH][SEQ][HD], pre-scaled by 1/8
    const unsigned short* __restrict__ kbuf,  // [BH][SEQ][HD]
    const unsigned short* __restrict__ vT,    // [BH][HD][SEQ]
    unsigned short* __restrict__ sa) {        // [B][SEQ][DMODEL]
  __shared__ __align__(16) char smem_raw[18432];
  auto k_lds = reinterpret_cast<unsigned short (*)[72]>(smem_raw);
  auto v_lds = reinterpret_cast<unsigned short (*)[72]>(smem_raw + 9216);
  auto o_merge = reinterpret_cast<float (*)[32][33]>(smem_raw);
  auto l_merge = reinterpret_cast<float (*)[32]>(smem_raw + 9216);

  const int tid = threadIdx.x, lane = tid & 63, w = tid >> 6;
  const int l31 = lane & 31, hi = lane >> 5;

  const int fid = (int)blockIdx.y * (int)gridDim.x + (int)blockIdx.x;  // 0..1535
  const int xcd = fid & 7, slot = fid >> 3;       // slot 0..191
  const int head3 = slot % 3;
  const int t = 63 - slot / 3;
  const int bh = head3 * 8 + xcd;
  const int ktmax = t >> 1;

  const size_t qk_base = (size_t)bh * SEQ * HD;
  const size_t v_base = (size_t)bh * HD * SEQ;
  const int bb = bh / NH, h = bh - bb * NH;

  const int sr = w * 32 + (lane >> 3);
  const int sc = (lane & 7) * 8;

  {
    bf16x8 rk[4], rv[4];
#pragma unroll
    for (int p = 0; p < 4; p++) {
      rk[p] = *(const bf16x8*)&kbuf[qk_base + (size_t)(sr + 8 * p) * HD + sc];
      rv[p] = *(const bf16x8*)&vT[v_base + (size_t)(sr + 8 * p) * SEQ + sc];
    }
#pragma unroll
    for (int p = 0; p < 4; p++) {
      *(bf16x8*)&k_lds[sr + 8 * p][sc] = rk[p];
      *(bf16x8*)&v_lds[sr + 8 * p][sc] = rv[p];
    }
  }

  bf16x8 aq[4];
#pragma unroll
  for (int ds = 0; ds < 4; ds++)
    aq[ds] = *(const bf16x8*)&qbuf[qk_base + (size_t)(t * 32 + l31) * HD + ds * 16 + hi * 8];

  f32x16 o0, o1;
#pragma unroll
  for (int i = 0; i < 16; i++) { o0[i] = 0.f; o1[i] = 0.f; }
  float lsum = 0.f;

  __syncthreads();

  for (int kt = 0; kt <= ktmax; ++kt) {
    const bool more = (kt < ktmax);
    bf16x8 rk[4], rv[4];
    if (more) {
      const int nrow = (kt + 1) * 64;
#pragma unroll
      for (int p = 0; p < 4; p++) {
        rk[p] = *(const bf16x8*)&kbuf[qk_base + (size_t)(nrow + sr + 8 * p) * HD + sc];
        rv[p] = *(const bf16x8*)&vT[v_base + (size_t)(sr + 8 * p) * SEQ + nrow + sc];
      }
    }

    f32x16 s;
#pragma unroll
    for (int i = 0; i < 16; i++) s[i] = 0.f;
    __builtin_amdgcn_s_setprio(1);
#pragma unroll
    for (int ds = 0; ds < 4; ds++) {
      bf16x8 bk = *(const bf16x8*)&k_lds[w * 32 + l31][ds * 16 + hi * 8];
      s = __builtin_amdgcn_mfma_f32_32x32x16_bf16(bk, aq[ds], s, 0, 0, 0);
    }
    __builtin_amdgcn_s_setprio(0);

    const bool diag = (kt == ktmax);
    const int qb2 = (t & 1) * 32;
#pragma unroll
    for (int r = 0; r < 16; r++) {
      int kr = (r & 3) + 8 * (r >> 2) + 4 * hi;
      float val = s[r];
      if (diag && (w * 32 + kr > qb2 + l31)) val = -1e30f;
      float p = __expf(val);
      s[r] = p;
      lsum += p;
    }

    union { unsigned int u[4]; bf16x8 v; } f1, f2;
    {
      unsigned int A = cvtpk(s[0], s[1]), B = cvtpk(s[2], s[3]);
      unsigned int C = cvtpk(s[4], s[5]), D = cvtpk(s[6], s[7]);
      auto rAC = __builtin_amdgcn_permlane32_swap(A, C, false, false);
      auto rBD = __builtin_amdgcn_permlane32_swap(B, D, false, false);
      f1.u[0] = rAC[0]; f1.u[1] = rBD[0]; f1.u[2] = rAC[1]; f1.u[3] = rBD[1];
      unsigned int A2 = cvtpk(s[8], s[9]),   B2 = cvtpk(s[10], s[11]);
      unsigned int C2 = cvtpk(s[12], s[13]), D2 = cvtpk(s[14], s[15]);
      auto rAC2 = __builtin_amdgcn_permlane32_swap(A2, C2, false, false);
      auto rBD2 = __builtin_amdgcn_permlane32_swap(B2, D2, false, false);
      f2.u[0] = rAC2[0]; f2.u[1] = rBD2[0]; f2.u[2] = rAC2[1]; f2.u[3] = rBD2[1];
    }

    __builtin_amdgcn_s_setprio(1);
    {
      bf16x8 bv00 = *(const bf16x8*)&v_lds[l31][w * 32 + hi * 8];
      bf16x8 bv01 = *(const bf16x8*)&v_lds[32 + l31][w * 32 + hi * 8];
      o0 = __builtin_amdgcn_mfma_f32_32x32x16_bf16(f1.v, bv00, o0, 0, 0, 0);
      o1 = __builtin_amdgcn_mfma_f32_32x32x16_bf16(f1.v, bv01, o1, 0, 0, 0);
      bf16x8 bv10 = *(const bf16x8*)&v_lds[l31][w * 32 + 16 + hi * 8];
      bf16x8 bv11 = *(const bf16x8*)&v_lds[32 + l31][w * 32 + 16 + hi * 8];
      o0 = __builtin_amdgcn_mfma_f32_32x32x16_bf16(f2.v, bv10, o0, 0, 0, 0);
      o1 = __builtin_amdgcn_mfma_f32_32x32x16_bf16(f2.v, bv11, o1, 0, 0, 0);
    }
    __builtin_amdgcn_s_setprio(0);

    if (more) {
      __syncthreads();
#pragma unroll
      for (int p = 0; p < 4; p++) {
        *(bf16x8*)&k_lds[sr + 8 * p][sc] = rk[p];
        *(bf16x8*)&v_lds[sr + 8 * p][sc] = rv[p];
      }
      __syncthreads();
    }
  }

  __syncthreads();
  {
    float ltot = lsum + __shfl_xor(lsum, 32);
    if (hi == 0) l_merge[w][l31] = ltot;
    f32x16 osend = w ? o0 : o1;
#pragma unroll
    for (int r = 0; r < 16; r++) {
      int ql = (r & 3) + 8 * (r >> 2) + 4 * hi;
      o_merge[w][ql][l31] = osend[r];
    }
    __syncthreads();
    f32x16 okeep = w ? o1 : o0;
#pragma unroll
    for (int r = 0; r < 16; r++) {
      int ql = (r & 3) + 8 * (r >> 2) + 4 * hi;
      float ot = okeep[r] + o_merge[1 - w][ql][l31];
      float lt = l_merge[0][ql] + l_merge[1][ql];
      sa[((size_t)bb * SEQ + t * 32 + ql) * DMODEL + h * HD + w * 32 + l31] = f2bf(ot / lt);
    }
  }
}

// ---------------- launch ----------------

extern "C" void kernel_launch(void* const* d_in, const int* in_sizes, int n_in,
                              void* d_out, int out_size, void* d_ws, size_t ws_size,
                              hipStream_t stream) {
  const float* x     = (const float*)d_in[0];
  const float* Wkqv  = (const float*)d_in[1];
  const float* bkqv  = (const float*)d_in[2];
  const float* Wproj = (const float*)d_in[3];
  const float* bproj = (const float*)d_in[4];
  float* out = (float*)d_out;

  char* ws = (char*)d_ws;
  unsigned short* x_bf   = (unsigned short*)(ws + 0);
  unsigned short* wkqvT  = (unsigned short*)(ws + 6291456);
  unsigned short* wprojT = (unsigned short*)(ws + 9830400);
  unsigned short* qb     = (unsigned short*)(ws + 11010048);
  unsigned short* kb     = (unsigned short*)(ws + 17301504);
  unsigned short* vT     = (unsigned short*)(ws + 23592960);
  unsigned short* sa     = (unsigned short*)(ws + 29884416);

  prep_kernel<<<NB_CVT + NB_T1 + NB_T2, 256, 0, stream>>>(
      x, x_bf, Wkqv, wkqvT, Wproj, wprojT);

  // GEMM1: 128x128 tiles, 8 waves/block (512 threads)
  gemm1_8w<<<dim3(N_KQV / 128, M_TOK / 128), 512, 0, stream>>>(
      x_bf, wkqvT, bkqv, kb, qb, vT);

  attn_kernel<<<dim3(64, BATCH * NH), 128, 0, stream>>>(qb, kb, vT, sa);

  // GEMM2: 64x64 tiles, 4 waves (unchanged round-15 schedule)
  gemm_bt<64, 64><<<dim3(DMODEL / 64, M_TOK / 64), 256, 0, stream>>>(
      sa, wprojT, bproj, M_TOK, DMODEL, DMODEL, out);
}

// Round 17
// 100.824 us; speedup vs baseline: 1.1181x; 1.0142x over previous
//
#include <hip/hip_runtime.h>

typedef __attribute__((ext_vector_type(8))) short bf16x8;
typedef __attribute__((ext_vector_type(4))) float f32x4;
typedef __attribute__((ext_vector_type(16))) float f32x16;

#define BATCH 2
#define SEQ 2048
#define DMODEL 768
#define NH 12
#define HD 64
#define M_TOK (BATCH * SEQ)   /* 4096 */
#define N_KQV (3 * DMODEL)    /* 2304 */

#define GLOAD16(gsrc, ldst) __builtin_amdgcn_global_load_lds( \
    (const __attribute__((address_space(1))) unsigned int*)(const void*)(gsrc), \
    (__attribute__((address_space(3))) unsigned int*)(void*)(ldst), 16, 0, 0)

__device__ __forceinline__ unsigned short f2bf(float f) {
  unsigned int u = __float_as_uint(f);
  u += 0x7FFFu + ((u >> 16) & 1u);
  return (unsigned short)(u >> 16);
}

__device__ __forceinline__ unsigned int cvtpk(float lo, float hi) {
  unsigned int r;
  asm("v_cvt_pk_bf16_f32 %0, %1, %2" : "=v"(r) : "v"(lo), "v"(hi));
  return r;
}

// ---------------- merged prep kernel ----------------
#define NB_CVT 3072                       /* 4096*768/4/256 */
#define NB_T1 (72 * 24)                   /* 2304/32 x 768/32 */
#define NB_T2 (24 * 24)                   /* 768/32 x 768/32 */

__global__ __launch_bounds__(256) void prep_kernel(
    const float* __restrict__ x, unsigned short* __restrict__ x_bf,
    const float* __restrict__ Wkqv, unsigned short* __restrict__ wkqvT,
    const float* __restrict__ Wproj, unsigned short* __restrict__ wprojT) {
  const int b = blockIdx.x;
  if (b < NB_CVT) {
    int i = b * 256 + threadIdx.x;
    float4 v = reinterpret_cast<const float4*>(x)[i];
    unsigned long long p = (unsigned long long)f2bf(v.x)
                         | ((unsigned long long)f2bf(v.y) << 16)
                         | ((unsigned long long)f2bf(v.z) << 32)
                         | ((unsigned long long)f2bf(v.w) << 48);
    reinterpret_cast<unsigned long long*>(x_bf)[i] = p;
    return;
  }
  __shared__ float tile[32][33];
  const float* in;
  unsigned short* out;
  int rows, cols, bx, by;
  if (b < NB_CVT + NB_T1) {
    int j = b - NB_CVT;
    in = Wkqv; out = wkqvT; rows = DMODEL; cols = N_KQV;
    bx = j % 72; by = j / 72;
  } else {
    int j = b - NB_CVT - NB_T1;
    in = Wproj; out = wprojT; rows = DMODEL; cols = DMODEL;
    bx = j % 24; by = j / 24;
  }
  const int tx = threadIdx.x & 31, ty = threadIdx.x >> 5;  // 32 x 8
  int c0 = bx * 32, r0 = by * 32;
  for (int i = ty; i < 32; i += 8)
    tile[i][tx] = in[(size_t)(r0 + i) * cols + c0 + tx];
  __syncthreads();
  for (int i = ty; i < 32; i += 8)
    out[(size_t)(c0 + i) * rows + r0 + tx] = f2bf(tile[tx][i]);
}

// ---------------- 8-wave 128x128 GEMM (round-16 verified body) ----------------
// 512 threads = 8 waves (4m x 2n), wave tile 32x64: 6 ds_read + 4 MFMA per
// wave-phase. Single-barrier 3-buffer counted-vmcnt schedule, XOR-swizzled
// LDS both sides. MODE 0: kqv split epilogue. MODE 1: f32 out + bias.
template <int MODE>
__global__ __launch_bounds__(512) void gemm_8w(
    const unsigned short* __restrict__ A,   // [M][K] bf16
    const unsigned short* __restrict__ BT,  // [N][K] bf16
    const float* __restrict__ bias,
    int NTOT,                               // N of output matrix (MODE1 row stride)
    unsigned short* __restrict__ outK, unsigned short* __restrict__ outQ,
    unsigned short* __restrict__ outVT, float* __restrict__ outF) {
  constexpr int K = DMODEL;
  __shared__ __align__(16) unsigned short lds_a[3][128][32];
  __shared__ __align__(16) unsigned short lds_b[3][128][32];
  const int tid = threadIdx.x;
  const int lane = tid & 63;
  const int w = tid >> 6;                  // 0..7
  const int wr = (w & 3) * 32;             // wave row base in tile
  const int wc = (w >> 2) * 64;            // wave col base in tile
  const int l31 = lane & 31, hi = lane >> 5;
  const int m0 = blockIdx.y * 128, n0 = blockIdx.x * 128;

  f32x16 acc[2];
#pragma unroll
  for (int nj = 0; nj < 2; nj++)
#pragma unroll
    for (int i = 0; i < 16; i++) acc[nj][i] = 0.f;

  const int srow = lane >> 2;                               // 0..15
  const int sg = ((lane & 3) ^ ((lane >> 3) & 3)) * 8;      // swizzled global k-chunk
  const int xq = (l31 >> 1) & 3;                            // read-side XOR

  // wave w<4 stages A rows [w*32, +32); w>=4 stages B rows [(w-4)*32, +32)
#define STAGE(buf, k0)                                                         \
  {                                                                            \
    if (w < 4) {                                                               \
      GLOAD16(&A[(size_t)(m0 + w * 32 + srow) * K + (k0) + sg],                \
              &lds_a[buf][w * 32][0]);                                         \
      GLOAD16(&A[(size_t)(m0 + w * 32 + 16 + srow) * K + (k0) + sg],           \
              &lds_a[buf][w * 32 + 16][0]);                                    \
    } else {                                                                   \
      GLOAD16(&BT[(size_t)(n0 + (w - 4) * 32 + srow) * K + (k0) + sg],         \
              &lds_b[buf][(w - 4) * 32][0]);                                   \
      GLOAD16(&BT[(size_t)(n0 + (w - 4) * 32 + 16 + srow) * K + (k0) + sg],    \
              &lds_b[buf][(w - 4) * 32 + 16][0]);                              \
    }                                                                          \
  }

  const int KT = K >> 5;   // 24
  STAGE(0, 0);
  STAGE(1, 32);

  int cur = 0;
  for (int kt = 0; kt < KT; ++kt) {
    // wait for stage kt (own-wave L=2); stage kt+1 stays in flight
    if (kt + 1 < KT) asm volatile("s_waitcnt vmcnt(2)" ::: "memory");
    else             asm volatile("s_waitcnt vmcnt(0)" ::: "memory");
    __builtin_amdgcn_s_barrier();
    __builtin_amdgcn_sched_barrier(0);

    bf16x8 aA[2], aB[2][2];
#pragma unroll
    for (int ds = 0; ds < 2; ds++) {
      const int rc = ((ds * 2 + hi) ^ xq) * 8;
      aA[ds] = *(const bf16x8*)&lds_a[cur][wr + l31][rc];
#pragma unroll
      for (int nj = 0; nj < 2; nj++)
        aB[ds][nj] = *(const bf16x8*)&lds_b[cur][wc + nj * 32 + l31][rc];
    }
#pragma unroll
    for (int ds = 0; ds < 2; ds++)
#pragma unroll
      for (int nj = 0; nj < 2; nj++)
        acc[nj] = __builtin_amdgcn_mfma_f32_32x32x16_bf16(aA[ds], aB[ds][nj], acc[nj], 0, 0, 0);

    // prefetch kt+2 into buf[(kt-1)%3]; readers exited at this barrier
    if (kt + 2 < KT) {
      const int nb = (cur + 2 >= 3) ? cur - 1 : cur + 2;
      STAGE(nb, (kt + 2) << 5);
    }
    cur = (cur == 2) ? 0 : cur + 1;
  }
#undef STAGE

#pragma unroll
  for (int nj = 0; nj < 2; nj++) {
#pragma unroll
    for (int r = 0; r < 16; r++) {
      int row = m0 + wr + (r & 3) + 8 * (r >> 2) + 4 * hi;
      int col = n0 + wc + nj * 32 + l31;
      float v = acc[nj][r] + bias[col];
      if (MODE == 0) {
        int chunk = col / DMODEL;          // 0=k, 1=q, 2=v
        int d = col - chunk * DMODEL;
        int hh = d >> 6, di = d & 63;
        int bb = row >> 11, tok = row & 2047;
        int bh = bb * NH + hh;
        if (chunk == 0)
          outK[((size_t)bh * SEQ + tok) * HD + di] = f2bf(v);
        else if (chunk == 1)
          outQ[((size_t)bh * SEQ + tok) * HD + di] = f2bf(v * 0.125f);
        else
          outVT[((size_t)bh * HD + di) * SEQ + tok] = f2bf(v);
      } else {
        outF[(size_t)row * NTOT + col] = v;
      }
    }
  }
}

// ---------------- flash attention (round-8 verified; t-major order) ----------------
__global__ __launch_bounds__(128) void attn_kernel(
    const unsigned short* __restrict__ qbuf,  // [BH][SEQ][HD], pre-scaled by 1/8
    const unsigned short* __restrict__ kbuf,  // [BH][SEQ][HD]
    const unsigned short* __restrict__ vT,    // [BH][HD][SEQ]
    unsigned short* __restrict__ sa) {        // [B][SEQ][DMODEL]
  __shared__ __align__(16) char smem_raw[18432];
  auto k_lds = reinterpret_cast<unsigned short (*)[72]>(smem_raw);
  auto v_lds = reinterpret_cast<unsigned short (*)[72]>(smem_raw + 9216);
  auto o_merge = reinterpret_cast<float (*)[32][33]>(smem_raw);
  auto l_merge = reinterpret_cast<float (*)[32]>(smem_raw + 9216);

  const int tid = threadIdx.x, lane = tid & 63, w = tid >> 6;
  const int l31 = lane & 31, hi = lane >> 5;

  const int fid = (int)blockIdx.y * (int)gridDim.x + (int)blockIdx.x;  // 0..1535
  const int xcd = fid & 7, slot = fid >> 3;       // slot 0..191
  const int head3 = slot % 3;
  const int t = 63 - slot / 3;
  const int bh = head3 * 8 + xcd;
  const int ktmax = t >> 1;

  const size_t qk_base = (size_t)bh * SEQ * HD;
  const size_t v_base = (size_t)bh * HD * SEQ;
  const int bb = bh / NH, h = bh - bb * NH;

  const int sr = w * 32 + (lane >> 3);
  const int sc = (lane & 7) * 8;

  {
    bf16x8 rk[4], rv[4];
#pragma unroll
    for (int p = 0; p < 4; p++) {
      rk[p] = *(const bf16x8*)&kbuf[qk_base + (size_t)(sr + 8 * p) * HD + sc];
      rv[p] = *(const bf16x8*)&vT[v_base + (size_t)(sr + 8 * p) * SEQ + sc];
    }
#pragma unroll
    for (int p = 0; p < 4; p++) {
      *(bf16x8*)&k_lds[sr + 8 * p][sc] = rk[p];
      *(bf16x8*)&v_lds[sr + 8 * p][sc] = rv[p];
    }
  }

  bf16x8 aq[4];
#pragma unroll
  for (int ds = 0; ds < 4; ds++)
    aq[ds] = *(const bf16x8*)&qbuf[qk_base + (size_t)(t * 32 + l31) * HD + ds * 16 + hi * 8];

  f32x16 o0, o1;
#pragma unroll
  for (int i = 0; i < 16; i++) { o0[i] = 0.f; o1[i] = 0.f; }
  float lsum = 0.f;

  __syncthreads();

  for (int kt = 0; kt <= ktmax; ++kt) {
    const bool more = (kt < ktmax);
    bf16x8 rk[4], rv[4];
    if (more) {
      const int nrow = (kt + 1) * 64;
#pragma unroll
      for (int p = 0; p < 4; p++) {
        rk[p] = *(const bf16x8*)&kbuf[qk_base + (size_t)(nrow + sr + 8 * p) * HD + sc];
        rv[p] = *(const bf16x8*)&vT[v_base + (size_t)(sr + 8 * p) * SEQ + nrow + sc];
      }
    }

    f32x16 s;
#pragma unroll
    for (int i = 0; i < 16; i++) s[i] = 0.f;
    __builtin_amdgcn_s_setprio(1);
#pragma unroll
    for (int ds = 0; ds < 4; ds++) {
      bf16x8 bk = *(const bf16x8*)&k_lds[w * 32 + l31][ds * 16 + hi * 8];
      s = __builtin_amdgcn_mfma_f32_32x32x16_bf16(bk, aq[ds], s, 0, 0, 0);
    }
    __builtin_amdgcn_s_setprio(0);

    const bool diag = (kt == ktmax);
    const int qb2 = (t & 1) * 32;
#pragma unroll
    for (int r = 0; r < 16; r++) {
      int kr = (r & 3) + 8 * (r >> 2) + 4 * hi;
      float val = s[r];
      if (diag && (w * 32 + kr > qb2 + l31)) val = -1e30f;
      float p = __expf(val);
      s[r] = p;
      lsum += p;
    }

    union { unsigned int u[4]; bf16x8 v; } f1, f2;
    {
      unsigned int A = cvtpk(s[0], s[1]), B = cvtpk(s[2], s[3]);
      unsigned int C = cvtpk(s[4], s[5]), D = cvtpk(s[6], s[7]);
      auto rAC = __builtin_amdgcn_permlane32_swap(A, C, false, false);
      auto rBD = __builtin_amdgcn_permlane32_swap(B, D, false, false);
      f1.u[0] = rAC[0]; f1.u[1] = rBD[0]; f1.u[2] = rAC[1]; f1.u[3] = rBD[1];
      unsigned int A2 = cvtpk(s[8], s[9]),   B2 = cvtpk(s[10], s[11]);
      unsigned int C2 = cvtpk(s[12], s[13]), D2 = cvtpk(s[14], s[15]);
      auto rAC2 = __builtin_amdgcn_permlane32_swap(A2, C2, false, false);
      auto rBD2 = __builtin_amdgcn_permlane32_swap(B2, D2, false, false);
      f2.u[0] = rAC2[0]; f2.u[1] = rBD2[0]; f2.u[2] = rAC2[1]; f2.u[3] = rBD2[1];
    }

    __builtin_amdgcn_s_setprio(1);
    {
      bf16x8 bv00 = *(const bf16x8*)&v_lds[l31][w * 32 + hi * 8];
      bf16x8 bv01 = *(const bf16x8*)&v_lds[32 + l31][w * 32 + hi * 8];
      o0 = __builtin_amdgcn_mfma_f32_32x32x16_bf16(f1.v, bv00, o0, 0, 0, 0);
      o1 = __builtin_amdgcn_mfma_f32_32x32x16_bf16(f1.v, bv01, o1, 0, 0, 0);
      bf16x8 bv10 = *(const bf16x8*)&v_lds[l31][w * 32 + 16 + hi * 8];
      bf16x8 bv11 = *(const bf16x8*)&v_lds[32 + l31][w * 32 + 16 + hi * 8];
      o0 = __builtin_amdgcn_mfma_f32_32x32x16_bf16(f2.v, bv10, o0, 0, 0, 0);
      o1 = __builtin_amdgcn_mfma_f32_32x32x16_bf16(f2.v, bv11, o1, 0, 0, 0);
    }
    __builtin_amdgcn_s_setprio(0);

    if (more) {
      __syncthreads();
#pragma unroll
      for (int p = 0; p < 4; p++) {
        *(bf16x8*)&k_lds[sr + 8 * p][sc] = rk[p];
        *(bf16x8*)&v_lds[sr + 8 * p][sc] = rv[p];
      }
      __syncthreads();
    }
  }

  __syncthreads();
  {
    float ltot = lsum + __shfl_xor(lsum, 32);
    if (hi == 0) l_merge[w][l31] = ltot;
    f32x16 osend = w ? o0 : o1;
#pragma unroll
    for (int r = 0; r < 16; r++) {
      int ql = (r & 3) + 8 * (r >> 2) + 4 * hi;
      o_merge[w][ql][l31] = osend[r];
    }
    __syncthreads();
    f32x16 okeep = w ? o1 : o0;
#pragma unroll
    for (int r = 0; r < 16; r++) {
      int ql = (r & 3) + 8 * (r >> 2) + 4 * hi;
      float ot = okeep[r] + o_merge[1 - w][ql][l31];
      float lt = l_merge[0][ql] + l_merge[1][ql];
      sa[((size_t)bb * SEQ + t * 32 + ql) * DMODEL + h * HD + w * 32 + l31] = f2bf(ot / lt);
    }
  }
}

// ---------------- launch ----------------

extern "C" void kernel_launch(void* const* d_in, const int* in_sizes, int n_in,
                              void* d_out, int out_size, void* d_ws, size_t ws_size,
                              hipStream_t stream) {
  const float* x     = (const float*)d_in[0];
  const float* Wkqv  = (const float*)d_in[1];
  const float* bkqv  = (const float*)d_in[2];
  const float* Wproj = (const float*)d_in[3];
  const float* bproj = (const float*)d_in[4];
  float* out = (float*)d_out;

  char* ws = (char*)d_ws;
  unsigned short* x_bf   = (unsigned short*)(ws + 0);
  unsigned short* wkqvT  = (unsigned short*)(ws + 6291456);
  unsigned short* wprojT = (unsigned short*)(ws + 9830400);
  unsigned short* qb     = (unsigned short*)(ws + 11010048);
  unsigned short* kb     = (unsigned short*)(ws + 17301504);
  unsigned short* vT     = (unsigned short*)(ws + 23592960);
  unsigned short* sa     = (unsigned short*)(ws + 29884416);

  prep_kernel<<<NB_CVT + NB_T1 + NB_T2, 256, 0, stream>>>(
      x, x_bf, Wkqv, wkqvT, Wproj, wprojT);

  // GEMM1: 128x128 tiles, 8 waves/block (512 threads), 576 blocks
  gemm_8w<0><<<dim3(N_KQV / 128, M_TOK / 128), 512, 0, stream>>>(
      x_bf, wkqvT, bkqv, N_KQV, kb, qb, vT, nullptr);

  attn_kernel<<<dim3(64, BATCH * NH), 128, 0, stream>>>(qb, kb, vT, sa);

  // GEMM2: 128x128 tiles, 8 waves/block, 192 blocks (all concurrent, 24 phases)
  gemm_8w<1><<<dim3(DMODEL / 128, M_TOK / 128), 512, 0, stream>>>(
      sa, wprojT, bproj, DMODEL, nullptr, nullptr, nullptr, out);
}